// Round 8
// baseline (418.790 us; speedup 1.0000x reference)
//
#include <hip/hip_runtime.h>
#include <math.h>

#define N_NODES 50000
#define N_EDGES 800000
#define FDIM 512                 // HEADS*OUT_CH
#define NEG_SLOPE 0.2f
#define CAP 64                   // bucket slots per node; in-deg ~Poisson(16), max~40

#define GEMM_BLKS 782            // ceil(50000/64)
#define FILL_BLKS 3125           // ceil(800000/256)

// ---------------------------------------------------------------------------
__device__ __forceinline__ unsigned short f2bf(float x) {
    unsigned int u = __float_as_uint(x);
    u = (u + 0x7FFFu + ((u >> 16) & 1u)) >> 16;   // round-to-nearest-even
    return (unsigned short)u;
}

// Fused preproc: blocks [0,GEMM_BLKS) compute x_l->bf16 table; blocks
// [GEMM_BLKS, GEMM_BLKS+FILL_BLKS) scatter edges into per-dst buckets.
__global__ __launch_bounds__(256) void preproc_kernel(const float* __restrict__ feat,
                                                      const float* __restrict__ Wl,
                                                      unsigned int* __restrict__ xlb,
                                                      const int* __restrict__ ei,
                                                      int* __restrict__ deg,
                                                      int* __restrict__ bucket) {
    int t = threadIdx.x;
    if (blockIdx.x >= GEMM_BLKS) {
        // ---- fill_bucket part ----
        bool is64 = true;
#pragma unroll
        for (int i = 0; i < 16; i++) is64 = is64 && (ei[2 * i + 1] == 0);
        int e = (blockIdx.x - GEMM_BLKS) * 256 + t;
        if (e < N_EDGES) {
            int src = is64 ? ei[2 * e] : ei[e];
            int dst = is64 ? ei[2 * (N_EDGES + e)] : ei[N_EDGES + e];
            int pos = atomicAdd(&deg[dst], 1);
            if (pos < CAP) bucket[dst * CAP + pos] = src;
        }
        return;
    }

    // ---- gemm_xl part ----
    __shared__ float fsh[64 * 16];
    int node0 = blockIdx.x * 64;
    int nvalid = min(64, N_NODES - node0);

    float w0[16], w1[16];
#pragma unroll
    for (int k = 0; k < 16; k++) {
        float2 w = ((const float2*)(Wl + k * FDIM))[t];
        w0[k] = w.x; w1[k] = w.y;
    }
    if (t < nvalid * 4) {
        ((float4*)fsh)[t] = ((const float4*)(feat + (size_t)node0 * 16))[t];
    }
    __syncthreads();

    for (int n = 0; n < nvalid; n++) {
        const float4* fq = (const float4*)(fsh + n * 16);
        float4 q0 = fq[0], q1 = fq[1], q2 = fq[2], q3 = fq[3];
        float fr[16] = {q0.x, q0.y, q0.z, q0.w, q1.x, q1.y, q1.z, q1.w,
                        q2.x, q2.y, q2.z, q2.w, q3.x, q3.y, q3.z, q3.w};
        float a0 = 0.f, a1 = 0.f;
#pragma unroll
        for (int k = 0; k < 16; k++) {
            a0 = fmaf(fr[k], w0[k], a0);
            a1 = fmaf(fr[k], w1[k], a1);
        }
        xlb[(size_t)(node0 + n) * 256 + t] =
            (unsigned int)f2bf(a0) | ((unsigned int)f2bf(a1) << 16);
    }
}

// ---------------------------------------------------------------------------
// DPP rotate-add within each 16-lane row (one head): cheap all-reduce.
#define DPP_ROR_ADD(x, ctrl) \
    ((x) + __int_as_float(__builtin_amdgcn_update_dpp(0, __float_as_int(x), (ctrl), 0xF, 0xF, true)))

__device__ __forceinline__ void unpack8(uint4 u, float* xv) {
    xv[0] = __uint_as_float(u.x << 16); xv[1] = __uint_as_float(u.x & 0xFFFF0000u);
    xv[2] = __uint_as_float(u.y << 16); xv[3] = __uint_as_float(u.y & 0xFFFF0000u);
    xv[4] = __uint_as_float(u.z << 16); xv[5] = __uint_as_float(u.z & 0xFFFF0000u);
    xv[6] = __uint_as_float(u.w << 16); xv[7] = __uint_as_float(u.w & 0xFFFF0000u);
}

__device__ __forceinline__ float partial_score(const float* xv, const float* xr, const float* a) {
    float p = 0.f;
#pragma unroll
    for (int j = 0; j < 8; j++) {
        float s = xv[j] + xr[j];
        float lr = fmaxf(s, NEG_SLOPE * s);   // leaky relu (slope in (0,1))
        p = fmaf(lr, a[j], p);
    }
    return p;
}

// Gather one batch of 4 edges: indices via one aligned int4, masked to the
// self-loop node beyond dn; 4 independent 16B row-gathers.
__device__ __forceinline__ void load_batch(const int* __restrict__ brow, int k, int dn,
                                           int node, const uint4* __restrict__ xlb,
                                           int lane, uint4* __restrict__ u) {
    int4 q = *(const int4*)(brow + k);
    int s0 = (k     < dn) ? q.x : node;
    int s1 = (k + 1 < dn) ? q.y : node;
    int s2 = (k + 2 < dn) ? q.z : node;
    int s3 = (k + 3 < dn) ? q.w : node;
    u[0] = xlb[(size_t)s0 * 64 + lane];
    u[1] = xlb[(size_t)s1 * 64 + lane];
    u[2] = xlb[(size_t)s2 * 64 + lane];
    u[3] = xlb[(size_t)s3 * 64 + lane];
}

__device__ __forceinline__ void process_batch(const uint4* __restrict__ u, int r,
                                              const float* __restrict__ xr,
                                              const float* __restrict__ a,
                                              float* __restrict__ acc,
                                              float& m, float& d) {
    float x0[8], x1[8], x2[8], x3[8];
    unpack8(u[0], x0); unpack8(u[1], x1); unpack8(u[2], x2); unpack8(u[3], x3);

    float p0 = partial_score(x0, xr, a);
    float p1 = partial_score(x1, xr, a);
    float p2 = partial_score(x2, xr, a);
    float p3 = partial_score(x3, xr, a);

    // interleaved DPP all-reduce within each 16-lane head group
    p0 = DPP_ROR_ADD(p0, 0x128); p1 = DPP_ROR_ADD(p1, 0x128);
    p2 = DPP_ROR_ADD(p2, 0x128); p3 = DPP_ROR_ADD(p3, 0x128);
    p0 = DPP_ROR_ADD(p0, 0x124); p1 = DPP_ROR_ADD(p1, 0x124);
    p2 = DPP_ROR_ADD(p2, 0x124); p3 = DPP_ROR_ADD(p3, 0x124);
    p0 = DPP_ROR_ADD(p0, 0x122); p1 = DPP_ROR_ADD(p1, 0x122);
    p2 = DPP_ROR_ADD(p2, 0x122); p3 = DPP_ROR_ADD(p3, 0x122);
    p0 = DPP_ROR_ADD(p0, 0x121); p1 = DPP_ROR_ADD(p1, 0x121);
    p2 = DPP_ROR_ADD(p2, 0x121); p3 = DPP_ROR_ADD(p3, 0x121);

    if (r < 2) p1 = -INFINITY;
    if (r < 3) p2 = -INFINITY;
    if (r < 4) p3 = -INFINITY;

    float nm = fmaxf(fmaxf(fmaxf(m, p0), fmaxf(p1, p2)), p3);
    float sc = __expf(m - nm);           // first batch: exp(-inf)=0
    float w0 = __expf(p0 - nm);
    float w1 = __expf(p1 - nm);
    float w2 = __expf(p2 - nm);
    float w3 = __expf(p3 - nm);
    d = fmaf(d, sc, (w0 + w1) + (w2 + w3));
#pragma unroll
    for (int j = 0; j < 8; j++) {
        float v = acc[j] * sc;
        v = fmaf(w0, x0[j], v);
        v = fmaf(w1, x1[j], v);
        v = fmaf(w2, x2[j], v);
        v = fmaf(w3, x3[j], v);
        acc[j] = v;
    }
    m = nm;
}

// One wave per destination node, 8 waves per block.
// 3-deep rotating pipeline: two batches of gathers in flight while one
// batch computes -> ~2 batches (~1000 cyc) of latency coverage.
__global__ __launch_bounds__(512) void gat_aggregate_kernel(
        const float* __restrict__ feat, const float* __restrict__ Wr,
        const float* __restrict__ att,  const float* __restrict__ bias,
        const uint4* __restrict__ xlb,  const int* __restrict__ deg,
        const int* __restrict__ bucket, float* __restrict__ out) {
    int t = threadIdx.x;
    int wave = t >> 6, lane = t & 63;
    int node = blockIdx.x * 8 + wave;    // grid*8 == N_NODES exactly
    int cbase = lane * 8;

    // feat[node] broadcast
    float f[16];
    {
        const float4* fp = (const float4*)(feat + (size_t)node * 16);
        float4 f0 = fp[0], f1 = fp[1], f2 = fp[2], f3 = fp[3];
        f[0]=f0.x; f[1]=f0.y; f[2]=f0.z; f[3]=f0.w;
        f[4]=f1.x; f[5]=f1.y; f[6]=f1.z; f[7]=f1.w;
        f[8]=f2.x; f[9]=f2.y; f[10]=f2.z; f[11]=f2.w;
        f[12]=f3.x; f[13]=f3.y; f[14]=f3.z; f[15]=f3.w;
    }

    // x_r[node] for this lane's 8 channels (W_r from global; L1/L2-resident)
    float xr[8];
#pragma unroll
    for (int j = 0; j < 8; j++) xr[j] = 0.f;
#pragma unroll
    for (int k = 0; k < 16; k++) {
        float fk = f[k];
        float4 wa = *(const float4*)(Wr + k * FDIM + cbase);
        float4 wb = *(const float4*)(Wr + k * FDIM + cbase + 4);
        xr[0] = fmaf(fk, wa.x, xr[0]); xr[1] = fmaf(fk, wa.y, xr[1]);
        xr[2] = fmaf(fk, wa.z, xr[2]); xr[3] = fmaf(fk, wa.w, xr[3]);
        xr[4] = fmaf(fk, wb.x, xr[4]); xr[5] = fmaf(fk, wb.y, xr[5]);
        xr[6] = fmaf(fk, wb.z, xr[6]); xr[7] = fmaf(fk, wb.w, xr[7]);
    }

    float a[8];
    {
        float4 a0 = *(const float4*)(att + cbase);
        float4 a1 = *(const float4*)(att + cbase + 4);
        a[0]=a0.x; a[1]=a0.y; a[2]=a0.z; a[3]=a0.w;
        a[4]=a1.x; a[5]=a1.y; a[6]=a1.z; a[7]=a1.w;
    }

    float m = -INFINITY, d = 0.f;
    float acc[8];
#pragma unroll
    for (int j = 0; j < 8; j++) acc[j] = 0.f;

    int dn = min(deg[node], CAP);
    int total = dn + 1;                       // + self loop
    const int* brow = bucket + node * CAP;

    uint4 A[4], B[4], C[4];
    load_batch(brow, 0, dn, node, xlb, lane, A);       // total >= 1 always
    if (4 < total) load_batch(brow, 4, dn, node, xlb, lane, B);

    int k = 0;
    while (true) {
        if (k + 8 < total)  load_batch(brow, k + 8,  dn, node, xlb, lane, C);
        process_batch(A, total - k, xr, a, acc, m, d);
        if (k + 4 >= total) break;
        if (k + 12 < total) load_batch(brow, k + 12, dn, node, xlb, lane, A);
        process_batch(B, total - (k + 4), xr, a, acc, m, d);
        if (k + 8 >= total) break;
        if (k + 16 < total) load_batch(brow, k + 16, dn, node, xlb, lane, B);
        process_batch(C, total - (k + 8), xr, a, acc, m, d);
        if (k + 12 >= total) break;
        k += 12;
    }

    float inv = 1.f / (d + 1e-16f);
    float4 b0 = *(const float4*)(bias + cbase);
    float4 b1 = *(const float4*)(bias + cbase + 4);
    float bb[8] = {b0.x, b0.y, b0.z, b0.w, b1.x, b1.y, b1.z, b1.w};
    float o[8];
#pragma unroll
    for (int j = 0; j < 8; j++) o[j] = fmaf(acc[j], inv, bb[j]);
    float* op = out + (size_t)node * FDIM + cbase;
    *(float4*)op       = make_float4(o[0], o[1], o[2], o[3]);
    *(float4*)(op + 4) = make_float4(o[4], o[5], o[6], o[7]);
}

// ---------------------------------------------------------------------------
extern "C" void kernel_launch(void* const* d_in, const int* in_sizes, int n_in,
                              void* d_out, int out_size, void* d_ws, size_t ws_size,
                              hipStream_t stream) {
    const float* feat = (const float*)d_in[0];
    const int*   ei   = (const int*)d_in[1];
    const float* Wl   = (const float*)d_in[2];
    const float* Wr   = (const float*)d_in[3];
    const float* att  = (const float*)d_in[4];
    const float* bias = (const float*)d_in[5];
    float* out = (float*)d_out;

    char* ws = (char*)d_ws;
    size_t off = 0;
    unsigned int* xlb = (unsigned int*)(ws + off); off += (size_t)N_NODES * 256 * sizeof(unsigned int);
    int* deg    = (int*)(ws + off); off += (size_t)N_NODES * sizeof(int);
    int* bucket = (int*)(ws + off); off += ((size_t)N_NODES * CAP + 16) * sizeof(int);
    (void)ws_size; (void)in_sizes; (void)n_in; (void)out_size;

    hipError_t _e = hipMemsetAsync(deg, 0, (size_t)N_NODES * sizeof(int), stream); (void)_e;
    preproc_kernel<<<GEMM_BLKS + FILL_BLKS, 256, 0, stream>>>(feat, Wl, xlb, ei, deg, bucket);
    gat_aggregate_kernel<<<N_NODES / 8, 512, 0, stream>>>(
        feat, Wr, att, bias, (const uint4*)xlb, deg, bucket, out);
}

// Round 10
// 333.519 us; speedup vs baseline: 1.2557x; 1.2557x over previous
//
#include <hip/hip_runtime.h>
#include <math.h>

#define N_NODES 50000
#define N_EDGES 800000
#define FDIM 512                 // HEADS*OUT_CH
#define NEG_SLOPE 0.2f
#define CAP 64                   // bucket slots per node; in-deg ~Poisson(16), max~40

#define GEMM_BLKS 782            // ceil(50000/64)
#define FILL_BLKS 3125           // ceil(800000/256)

typedef _Float16 v2h __attribute__((ext_vector_type(2)));
typedef _Float16 v8h __attribute__((ext_vector_type(8)));

__device__ __forceinline__ v2h pack_h2(float a, float b) {
    v2h r; r.x = (_Float16)a; r.y = (_Float16)b; return r;
}

// ---------------------------------------------------------------------------
// Fused preproc: blocks [0,GEMM_BLKS) compute x_l -> fp16 table; blocks
// [GEMM_BLKS, ...) scatter edges into per-dst buckets.
__global__ __launch_bounds__(256) void preproc_kernel(const float* __restrict__ feat,
                                                      const float* __restrict__ Wl,
                                                      unsigned int* __restrict__ xlb,
                                                      const int* __restrict__ ei,
                                                      int* __restrict__ deg,
                                                      int* __restrict__ bucket) {
    int t = threadIdx.x;
    if (blockIdx.x >= GEMM_BLKS) {
        // ---- fill_bucket part ----
        bool is64 = true;
#pragma unroll
        for (int i = 0; i < 16; i++) is64 = is64 && (ei[2 * i + 1] == 0);
        int e = (blockIdx.x - GEMM_BLKS) * 256 + t;
        if (e < N_EDGES) {
            int src = is64 ? ei[2 * e] : ei[e];
            int dst = is64 ? ei[2 * (N_EDGES + e)] : ei[N_EDGES + e];
            int pos = atomicAdd(&deg[dst], 1);
            if (pos < CAP) bucket[dst * CAP + pos] = src;
        }
        return;
    }

    // ---- gemm_xl part: x_l = feat @ W_l, stored as packed fp16 pairs ----
    __shared__ float fsh[64 * 16];
    int node0 = blockIdx.x * 64;
    int nvalid = min(64, N_NODES - node0);

    float w0[16], w1[16];
#pragma unroll
    for (int k = 0; k < 16; k++) {
        float2 w = ((const float2*)(Wl + k * FDIM))[t];
        w0[k] = w.x; w1[k] = w.y;
    }
    if (t < nvalid * 4) {
        ((float4*)fsh)[t] = ((const float4*)(feat + (size_t)node0 * 16))[t];
    }
    __syncthreads();

    for (int n = 0; n < nvalid; n++) {
        const float4* fq = (const float4*)(fsh + n * 16);
        float4 q0 = fq[0], q1 = fq[1], q2 = fq[2], q3 = fq[3];
        float fr[16] = {q0.x, q0.y, q0.z, q0.w, q1.x, q1.y, q1.z, q1.w,
                        q2.x, q2.y, q2.z, q2.w, q3.x, q3.y, q3.z, q3.w};
        float a0 = 0.f, a1 = 0.f;
#pragma unroll
        for (int k = 0; k < 16; k++) {
            a0 = fmaf(fr[k], w0[k], a0);
            a1 = fmaf(fr[k], w1[k], a1);
        }
        v2h hv = pack_h2(a0, a1);
        xlb[(size_t)(node0 + n) * 256 + t] = __builtin_bit_cast(unsigned int, hv);
    }
}

// ---------------------------------------------------------------------------
// DPP rotate-add within each 16-lane row (one head): cheap all-reduce.
#define DPP_ROR_ADD(x, ctrl) \
    ((x) + __int_as_float(__builtin_amdgcn_update_dpp(0, __float_as_int(x), (ctrl), 0xF, 0xF, true)))

// Per-lane partial score over 8 fp16 channels, packed f16 math.
__device__ __forceinline__ float score8(uint4 u, const v2h* __restrict__ xr2,
                                        const v2h* __restrict__ a2, v2h sl) {
    v2h x0 = __builtin_bit_cast(v2h, u.x);
    v2h x1 = __builtin_bit_cast(v2h, u.y);
    v2h x2 = __builtin_bit_cast(v2h, u.z);
    v2h x3 = __builtin_bit_cast(v2h, u.w);
    v2h ps = {(_Float16)0.f, (_Float16)0.f};
    v2h s;
    s = x0 + xr2[0]; ps += __builtin_elementwise_max(s, s * sl) * a2[0];
    s = x1 + xr2[1]; ps += __builtin_elementwise_max(s, s * sl) * a2[1];
    s = x2 + xr2[2]; ps += __builtin_elementwise_max(s, s * sl) * a2[2];
    s = x3 + xr2[3]; ps += __builtin_elementwise_max(s, s * sl) * a2[3];
    return (float)ps.x + (float)ps.y;
}

// Gather one batch of 4 edges; 32-bit byte offsets (row = 1 KB, table 51 MB).
__device__ __forceinline__ void load_batch(const int* __restrict__ brow, int k, int dn,
                                           int node, const char* __restrict__ xlb_b,
                                           unsigned lane16, uint4* __restrict__ u) {
    int4 q = *(const int4*)(brow + k);
    unsigned o0 = ((unsigned)((k     < dn) ? q.x : node) << 10) + lane16;
    unsigned o1 = ((unsigned)((k + 1 < dn) ? q.y : node) << 10) + lane16;
    unsigned o2 = ((unsigned)((k + 2 < dn) ? q.z : node) << 10) + lane16;
    unsigned o3 = ((unsigned)((k + 3 < dn) ? q.w : node) << 10) + lane16;
    u[0] = *(const uint4*)(xlb_b + o0);
    u[1] = *(const uint4*)(xlb_b + o1);
    u[2] = *(const uint4*)(xlb_b + o2);
    u[3] = *(const uint4*)(xlb_b + o3);
}

__device__ __forceinline__ void process_batch(const uint4* __restrict__ u, int r,
                                              const v2h* __restrict__ xr2,
                                              const v2h* __restrict__ a2, v2h sl,
                                              float* __restrict__ acc,
                                              float& m, float& d) {
    float p0 = score8(u[0], xr2, a2, sl);
    float p1 = score8(u[1], xr2, a2, sl);
    float p2 = score8(u[2], xr2, a2, sl);
    float p3 = score8(u[3], xr2, a2, sl);

    // interleaved DPP all-reduce within each 16-lane head group
    p0 = DPP_ROR_ADD(p0, 0x128); p1 = DPP_ROR_ADD(p1, 0x128);
    p2 = DPP_ROR_ADD(p2, 0x128); p3 = DPP_ROR_ADD(p3, 0x128);
    p0 = DPP_ROR_ADD(p0, 0x124); p1 = DPP_ROR_ADD(p1, 0x124);
    p2 = DPP_ROR_ADD(p2, 0x124); p3 = DPP_ROR_ADD(p3, 0x124);
    p0 = DPP_ROR_ADD(p0, 0x122); p1 = DPP_ROR_ADD(p1, 0x122);
    p2 = DPP_ROR_ADD(p2, 0x122); p3 = DPP_ROR_ADD(p3, 0x122);
    p0 = DPP_ROR_ADD(p0, 0x121); p1 = DPP_ROR_ADD(p1, 0x121);
    p2 = DPP_ROR_ADD(p2, 0x121); p3 = DPP_ROR_ADD(p3, 0x121);

    if (r < 2) p1 = -INFINITY;
    if (r < 3) p2 = -INFINITY;
    if (r < 4) p3 = -INFINITY;

    float nm = fmaxf(fmaxf(fmaxf(m, p0), fmaxf(p1, p2)), p3);
    float sc = __expf(m - nm);           // first batch: exp(-inf)=0
    float w0 = __expf(p0 - nm);
    float w1 = __expf(p1 - nm);
    float w2 = __expf(p2 - nm);
    float w3 = __expf(p3 - nm);
    d = fmaf(d, sc, (w0 + w1) + (w2 + w3));

    v8h h0 = __builtin_bit_cast(v8h, u[0]);
    v8h h1 = __builtin_bit_cast(v8h, u[1]);
    v8h h2 = __builtin_bit_cast(v8h, u[2]);
    v8h h3 = __builtin_bit_cast(v8h, u[3]);
#pragma unroll
    for (int j = 0; j < 8; j++) {
        float v = acc[j] * sc;
        v = fmaf(w0, (float)h0[j], v);   // v_fma_mix-fusable
        v = fmaf(w1, (float)h1[j], v);
        v = fmaf(w2, (float)h2[j], v);
        v = fmaf(w3, (float)h3[j], v);
        acc[j] = v;
    }
    m = nm;
}

// One wave per destination node, 8 waves per block, 2-deep ping-pong (r7
// structure: VGPR 64, occupancy 34% — proven best; r8's 3-deep regressed).
__global__ __launch_bounds__(512) void gat_aggregate_kernel(
        const float* __restrict__ feat, const float* __restrict__ Wr,
        const float* __restrict__ att,  const float* __restrict__ bias,
        const char* __restrict__ xlb_b, const int* __restrict__ deg,
        const int* __restrict__ bucket, float* __restrict__ out) {
    int t = threadIdx.x;
    int wave = t >> 6, lane = t & 63;
    int node = blockIdx.x * 8 + wave;    // grid*8 == N_NODES exactly
    int cbase = lane * 8;
    unsigned lane16 = (unsigned)lane << 4;

    // feat[node] broadcast
    float f[16];
    {
        const float4* fp = (const float4*)(feat + (size_t)node * 16);
        float4 f0 = fp[0], f1 = fp[1], f2 = fp[2], f3 = fp[3];
        f[0]=f0.x; f[1]=f0.y; f[2]=f0.z; f[3]=f0.w;
        f[4]=f1.x; f[5]=f1.y; f[6]=f1.z; f[7]=f1.w;
        f[8]=f2.x; f[9]=f2.y; f[10]=f2.z; f[11]=f2.w;
        f[12]=f3.x; f[13]=f3.y; f[14]=f3.z; f[15]=f3.w;
    }

    // x_r[node] for this lane's 8 channels, fp32 accumulate then pack to fp16
    float xr[8];
#pragma unroll
    for (int j = 0; j < 8; j++) xr[j] = 0.f;
#pragma unroll
    for (int k = 0; k < 16; k++) {
        float fk = f[k];
        float4 wa = *(const float4*)(Wr + k * FDIM + cbase);
        float4 wb = *(const float4*)(Wr + k * FDIM + cbase + 4);
        xr[0] = fmaf(fk, wa.x, xr[0]); xr[1] = fmaf(fk, wa.y, xr[1]);
        xr[2] = fmaf(fk, wa.z, xr[2]); xr[3] = fmaf(fk, wa.w, xr[3]);
        xr[4] = fmaf(fk, wb.x, xr[4]); xr[5] = fmaf(fk, wb.y, xr[5]);
        xr[6] = fmaf(fk, wb.z, xr[6]); xr[7] = fmaf(fk, wb.w, xr[7]);
    }
    v2h xr2[4];
    xr2[0] = pack_h2(xr[0], xr[1]);
    xr2[1] = pack_h2(xr[2], xr[3]);
    xr2[2] = pack_h2(xr[4], xr[5]);
    xr2[3] = pack_h2(xr[6], xr[7]);

    v2h a2[4];
    {
        float4 a0 = *(const float4*)(att + cbase);
        float4 a1 = *(const float4*)(att + cbase + 4);
        a2[0] = pack_h2(a0.x, a0.y);
        a2[1] = pack_h2(a0.z, a0.w);
        a2[2] = pack_h2(a1.x, a1.y);
        a2[3] = pack_h2(a1.z, a1.w);
    }
    const v2h sl = {(_Float16)NEG_SLOPE, (_Float16)NEG_SLOPE};

    float m = -INFINITY, d = 0.f;
    float acc[8];
#pragma unroll
    for (int j = 0; j < 8; j++) acc[j] = 0.f;

    int dn = min(deg[node], CAP);
    int total = dn + 1;                       // + self loop
    const int* brow = bucket + node * CAP;

    uint4 A[4], B[4];
    load_batch(brow, 0, dn, node, xlb_b, lane16, A);   // total >= 1 always
    int k = 0;
    while (true) {
        int kB = k + 4;
        bool hasB = kB < total;
        if (hasB) load_batch(brow, kB, dn, node, xlb_b, lane16, B);
        process_batch(A, total - k, xr2, a2, sl, acc, m, d);
        if (!hasB) break;
        int kA = k + 8;
        bool hasA = kA < total;
        if (hasA) load_batch(brow, kA, dn, node, xlb_b, lane16, A);
        process_batch(B, total - kB, xr2, a2, sl, acc, m, d);
        if (!hasA) break;
        k = kA;
    }

    float inv = 1.f / (d + 1e-16f);
    float4 b0 = *(const float4*)(bias + cbase);
    float4 b1 = *(const float4*)(bias + cbase + 4);
    float bb[8] = {b0.x, b0.y, b0.z, b0.w, b1.x, b1.y, b1.z, b1.w};
    float o[8];
#pragma unroll
    for (int j = 0; j < 8; j++) o[j] = fmaf(acc[j], inv, bb[j]);
    float* op = out + (size_t)node * FDIM + cbase;
    *(float4*)op       = make_float4(o[0], o[1], o[2], o[3]);
    *(float4*)(op + 4) = make_float4(o[4], o[5], o[6], o[7]);
}

// ---------------------------------------------------------------------------
extern "C" void kernel_launch(void* const* d_in, const int* in_sizes, int n_in,
                              void* d_out, int out_size, void* d_ws, size_t ws_size,
                              hipStream_t stream) {
    const float* feat = (const float*)d_in[0];
    const int*   ei   = (const int*)d_in[1];
    const float* Wl   = (const float*)d_in[2];
    const float* Wr   = (const float*)d_in[3];
    const float* att  = (const float*)d_in[4];
    const float* bias = (const float*)d_in[5];
    float* out = (float*)d_out;

    char* ws = (char*)d_ws;
    size_t off = 0;
    unsigned int* xlb = (unsigned int*)(ws + off); off += (size_t)N_NODES * 256 * sizeof(unsigned int);
    int* deg    = (int*)(ws + off); off += (size_t)N_NODES * sizeof(int);
    int* bucket = (int*)(ws + off); off += ((size_t)N_NODES * CAP + 16) * sizeof(int);
    (void)ws_size; (void)in_sizes; (void)n_in; (void)out_size;

    hipError_t _e = hipMemsetAsync(deg, 0, (size_t)N_NODES * sizeof(int), stream); (void)_e;
    preproc_kernel<<<GEMM_BLKS + FILL_BLKS, 256, 0, stream>>>(feat, Wl, xlb, ei, deg, bucket);
    gat_aggregate_kernel<<<N_NODES / 8, 512, 0, stream>>>(
        feat, Wr, att, bias, (const char*)xlb, deg, bucket, out);
}